// Round 1
// baseline (7397.495 us; speedup 1.0000x reference)
//
#include <hip/hip_runtime.h>
#include <math.h>

#define SS 50
#define BB 2048
#define HH 128
#define DD 256
#define STEPS 49

__device__ __forceinline__ float sigmoidf_(float x) { return 1.0f / (1.0f + expf(-x)); }

// ---------------------------------------------------------------------------
// K0: init — x0 = tanh(fe @ W_first^T + b_first), q <- [h0_f | h0_b], c <- c0,
// mask = 0, lp = 0.   grid = B*D/256
// ---------------------------------------------------------------------------
__global__ __launch_bounds__(256) void k_init(
    const float* __restrict__ h0, const float* __restrict__ c0,
    const float* __restrict__ rk, const float* __restrict__ Wf,
    const float* __restrict__ bf,
    float* __restrict__ x, float* __restrict__ q, float* __restrict__ c,
    float* __restrict__ mask, float* __restrict__ lp)
{
    int idx = blockIdx.x * 256 + threadIdx.x;      // 0 .. B*D-1
    int b = idx >> 8, d = idx & 255;
    float inv = 1.0f / rk[b];
    float t0 = 1.1f * Wf[2 * d] + inv * Wf[2 * d + 1];
    x[idx] = tanhf(t0 + bf[d]);
    q[idx] = (d < HH) ? h0[b * HH + d] : h0[BB * HH + b * HH + (d - HH)];
    if (idx < 2 * BB * HH) c[idx] = c0[idx];
    if (idx < BB * SS) mask[idx] = 0.0f;
    if (idx < BB) lp[idx] = 0.0f;
}

// ---------------------------------------------------------------------------
// P1: refX[b][s][d] = sum_e WrefX[d][e] * enc[s][b][e]
// M = B*S rows (n = b*S+s), N = D = 256 (full width per block), K = 256.
// tile 64(M) x 256(N), 256 threads, acc 4x16.  grid (1600, 1, 2)
// ---------------------------------------------------------------------------
__global__ __launch_bounds__(256) void k_refdot(
    const float* __restrict__ enc, const float* __restrict__ Wg,
    const float* __restrict__ Wp, float* __restrict__ refg,
    float* __restrict__ refp)
{
    const float* W = blockIdx.z ? Wp : Wg;
    float* out = blockIdx.z ? refp : refg;
    __shared__ float As[16][68];
    __shared__ float Ws[16][264];
    int t = threadIdx.x;
    int m0 = blockIdx.x * 64;
    int rr = t >> 2, kk = (t & 3) << 2;
    int n = m0 + rr;
    int ab = n / SS, as = n - ab * SS;
    const float* arow = enc + ((size_t)as * BB + ab) * DD + kk;
    const float* wrow = W + (size_t)t * DD;
    int tm = (t & 15) << 2;
    int tn = (t >> 4) << 4;
    float acc[4][16];
#pragma unroll
    for (int i = 0; i < 4; i++)
#pragma unroll
        for (int j = 0; j < 16; j++) acc[i][j] = 0.0f;

    for (int k0 = 0; k0 < DD; k0 += 16) {
        float4 av = *(const float4*)(arow + k0);
        float4 w0 = *(const float4*)(wrow + k0);
        float4 w1 = *(const float4*)(wrow + k0 + 4);
        float4 w2 = *(const float4*)(wrow + k0 + 8);
        float4 w3 = *(const float4*)(wrow + k0 + 12);
        __syncthreads();
        As[kk + 0][rr] = av.x; As[kk + 1][rr] = av.y;
        As[kk + 2][rr] = av.z; As[kk + 3][rr] = av.w;
        Ws[0][t] = w0.x;  Ws[1][t] = w0.y;  Ws[2][t] = w0.z;  Ws[3][t] = w0.w;
        Ws[4][t] = w1.x;  Ws[5][t] = w1.y;  Ws[6][t] = w1.z;  Ws[7][t] = w1.w;
        Ws[8][t] = w2.x;  Ws[9][t] = w2.y;  Ws[10][t] = w2.z; Ws[11][t] = w2.w;
        Ws[12][t] = w3.x; Ws[13][t] = w3.y; Ws[14][t] = w3.z; Ws[15][t] = w3.w;
        __syncthreads();
#pragma unroll
        for (int k = 0; k < 16; k++) {
            float4 a = *(const float4*)&As[k][tm];
            float aa[4] = {a.x, a.y, a.z, a.w};
#pragma unroll
            for (int jj = 0; jj < 4; jj++) {
                float4 w = *(const float4*)&Ws[k][tn + (jj << 2)];
                float ww[4] = {w.x, w.y, w.z, w.w};
#pragma unroll
                for (int i = 0; i < 4; i++)
#pragma unroll
                    for (int cj = 0; cj < 4; cj++)
                        acc[i][jj * 4 + cj] = fmaf(aa[i], ww[cj], acc[i][jj * 4 + cj]);
            }
        }
    }
#pragma unroll
    for (int i = 0; i < 4; i++) {
        float* orow = out + (size_t)(m0 + tm + i) * DD + tn;
#pragma unroll
        for (int jj = 0; jj < 4; jj++) {
            float4 o = make_float4(acc[i][jj * 4], acc[i][jj * 4 + 1],
                                   acc[i][jj * 4 + 2], acc[i][jj * 4 + 3]);
            *(float4*)(orow + (jj << 2)) = o;
        }
    }
}

// ---------------------------------------------------------------------------
// K1: gates[b][z*512 + j] = x[b]·Wih_z[j] + h_z[b]·Whh_z[j] + bih_z[j] + bhh_z[j]
// M=2048, N=512 (per dir), K=384 (256 x + 128 h). tile 64x64. grid (32,8,2)
// ---------------------------------------------------------------------------
__global__ __launch_bounds__(256) void k_gates(
    const float* __restrict__ x, const float* __restrict__ q,
    const float* __restrict__ Wih_f, const float* __restrict__ Whh_f,
    const float* __restrict__ bih_f, const float* __restrict__ bhh_f,
    const float* __restrict__ Wih_b, const float* __restrict__ Whh_b,
    const float* __restrict__ bih_b, const float* __restrict__ bhh_b,
    float* __restrict__ gates)
{
    int z = blockIdx.z;
    const float* Wih = z ? Wih_b : Wih_f;
    const float* Whh = z ? Whh_b : Whh_f;
    const float* bih = z ? bih_b : bih_f;
    const float* bhh = z ? bhh_b : bhh_f;
    __shared__ float As[16][68];
    __shared__ float Ws[16][68];
    int t = threadIdx.x;
    int m0 = blockIdx.x * 64, n0 = blockIdx.y * 64;
    int rr = t >> 2, kk = (t & 3) << 2;
    int tm = (t & 15) << 2, tn = (t >> 4) << 2;
    float acc[4][4] = {};
    for (int k0 = 0; k0 < 384; k0 += 16) {
        float4 av, wv;
        if (k0 < 256) {
            av = *(const float4*)(x + (size_t)(m0 + rr) * DD + k0 + kk);
            wv = *(const float4*)(Wih + (size_t)(n0 + rr) * DD + k0 + kk);
        } else {
            av = *(const float4*)(q + (size_t)(m0 + rr) * DD + (z << 7) + (k0 - 256) + kk);
            wv = *(const float4*)(Whh + (size_t)(n0 + rr) * HH + (k0 - 256) + kk);
        }
        __syncthreads();
        As[kk + 0][rr] = av.x; As[kk + 1][rr] = av.y;
        As[kk + 2][rr] = av.z; As[kk + 3][rr] = av.w;
        Ws[kk + 0][rr] = wv.x; Ws[kk + 1][rr] = wv.y;
        Ws[kk + 2][rr] = wv.z; Ws[kk + 3][rr] = wv.w;
        __syncthreads();
#pragma unroll
        for (int k = 0; k < 16; k++) {
            float4 a = *(const float4*)&As[k][tm];
            float4 w = *(const float4*)&Ws[k][tn];
            float aa[4] = {a.x, a.y, a.z, a.w};
            float ww[4] = {w.x, w.y, w.z, w.w};
#pragma unroll
            for (int i = 0; i < 4; i++)
#pragma unroll
                for (int j = 0; j < 4; j++)
                    acc[i][j] = fmaf(aa[i], ww[j], acc[i][j]);
        }
    }
#pragma unroll
    for (int i = 0; i < 4; i++) {
        int col = n0 + tn;
        float4 o;
        o.x = acc[i][0] + bih[col + 0] + bhh[col + 0];
        o.y = acc[i][1] + bih[col + 1] + bhh[col + 1];
        o.z = acc[i][2] + bih[col + 2] + bhh[col + 2];
        o.w = acc[i][3] + bih[col + 3] + bhh[col + 3];
        *(float4*)(gates + (size_t)(m0 + tm + i) * 1024 + (z << 9) + col) = o;
    }
}

// ---------------------------------------------------------------------------
// K2: LSTM pointwise.  idx over 2*B*H.  grid 2048
// ---------------------------------------------------------------------------
__global__ __launch_bounds__(256) void k_lstm_pw(
    const float* __restrict__ gates, float* __restrict__ q, float* __restrict__ c)
{
    int idx = blockIdx.x * 256 + threadIdx.x;   // 0 .. 2*B*H-1
    int z = idx >> 18;                          // B*H = 2^18
    int r = idx & (BB * HH - 1);
    int b = r >> 7, hh = r & 127;
    const float* gb = gates + (size_t)b * 1024 + (z << 9);
    float ig = sigmoidf_(gb[hh]);
    float fg = sigmoidf_(gb[128 + hh]);
    float gg = tanhf(gb[256 + hh]);
    float og = sigmoidf_(gb[384 + hh]);
    float c2 = fg * c[idx] + ig * gg;
    c[idx] = c2;
    q[(size_t)b * DD + (z << 7) + hh] = og * tanhf(c2);
}

// ---------------------------------------------------------------------------
// K3/K6: out[b][d] = sum_e A[b][e] * W[d][e]   (M=2048,N=256,K=256). grid (32,4)
// ---------------------------------------------------------------------------
__global__ __launch_bounds__(256) void k_proj(
    const float* __restrict__ A, const float* __restrict__ W, float* __restrict__ out)
{
    __shared__ float As[16][68];
    __shared__ float Ws[16][68];
    int t = threadIdx.x;
    int m0 = blockIdx.x * 64, n0 = blockIdx.y * 64;
    int rr = t >> 2, kk = (t & 3) << 2;
    int tm = (t & 15) << 2, tn = (t >> 4) << 2;
    const float* arow = A + (size_t)(m0 + rr) * DD + kk;
    const float* wrow = W + (size_t)(n0 + rr) * DD + kk;
    float acc[4][4] = {};
    for (int k0 = 0; k0 < DD; k0 += 16) {
        float4 av = *(const float4*)(arow + k0);
        float4 wv = *(const float4*)(wrow + k0);
        __syncthreads();
        As[kk + 0][rr] = av.x; As[kk + 1][rr] = av.y;
        As[kk + 2][rr] = av.z; As[kk + 3][rr] = av.w;
        Ws[kk + 0][rr] = wv.x; Ws[kk + 1][rr] = wv.y;
        Ws[kk + 2][rr] = wv.z; Ws[kk + 3][rr] = wv.w;
        __syncthreads();
#pragma unroll
        for (int k = 0; k < 16; k++) {
            float4 a = *(const float4*)&As[k][tm];
            float4 w = *(const float4*)&Ws[k][tn];
            float aa[4] = {a.x, a.y, a.z, a.w};
            float ww[4] = {w.x, w.y, w.z, w.w};
#pragma unroll
            for (int i = 0; i < 4; i++)
#pragma unroll
                for (int j = 0; j < 4; j++)
                    acc[i][j] = fmaf(aa[i], ww[j], acc[i][j]);
        }
    }
#pragma unroll
    for (int i = 0; i < 4; i++) {
        float4 o = make_float4(acc[i][0], acc[i][1], acc[i][2], acc[i][3]);
        *(float4*)(out + (size_t)(m0 + tm + i) * DD + n0 + tn) = o;
    }
}

// ---------------------------------------------------------------------------
// KG: glimpse. one block per b; u_g -> masked softmax -> g_l. grid (B), 256 thr
// ---------------------------------------------------------------------------
__global__ __launch_bounds__(256) void k_glimpse(
    const float* __restrict__ refg, const float* __restrict__ qW,
    const float* __restrict__ vg, const float* __restrict__ enc,
    const float* __restrict__ mask, float* __restrict__ gl)
{
    int b = blockIdx.x;
    int t = threadIdx.x, wave = t >> 6, lane = t & 63;
    __shared__ float ash[SS];
    int d0 = lane << 2;
    float4 qw = *(const float4*)(qW + (size_t)b * DD + d0);
    float4 vv = *(const float4*)(vg + d0);
    for (int s = wave; s < SS; s += 4) {
        float4 r = *(const float4*)(refg + ((size_t)b * SS + s) * DD + d0);
        float sum = vv.x * tanhf(r.x + qw.x) + vv.y * tanhf(r.y + qw.y) +
                    vv.z * tanhf(r.z + qw.z) + vv.w * tanhf(r.w + qw.w);
#pragma unroll
        for (int off = 32; off; off >>= 1) sum += __shfl_xor(sum, off);
        if (lane == 0) ash[s] = sum;
    }
    __syncthreads();
    if (t < 64) {
        float logit = (t < SS && mask[b * SS + t] == 0.0f) ? ash[t]
                                                           : -__builtin_inff();
        float m = logit;
#pragma unroll
        for (int off = 32; off; off >>= 1) m = fmaxf(m, __shfl_xor(m, off));
        float e = expf(logit - m);
        float ssum = e;
#pragma unroll
        for (int off = 32; off; off >>= 1) ssum += __shfl_xor(ssum, off);
        if (t < SS) ash[t] = e / ssum;
    }
    __syncthreads();
    float accv = 0.0f;
    for (int s = 0; s < SS; ++s)
        accv = fmaf(ash[s], enc[((size_t)s * BB + b) * DD + t], accv);
    gl[(size_t)b * DD + t] = accv;
}

// ---------------------------------------------------------------------------
// KP: pointer. one block per b; u_p -> argmax (first-max) -> lp, mask, sel,
// next input gather.  grid (B), 256 thr
// ---------------------------------------------------------------------------
__global__ __launch_bounds__(256) void k_pointer(
    const float* __restrict__ refp, const float* __restrict__ gW,
    const float* __restrict__ vp, const float* __restrict__ enc,
    float* __restrict__ mask, float* __restrict__ x,
    float* __restrict__ lp, float* __restrict__ outp, int step)
{
    int b = blockIdx.x;
    int t = threadIdx.x, wave = t >> 6, lane = t & 63;
    __shared__ float ash[SS];
    __shared__ int ssel;
    int d0 = lane << 2;
    float4 gw = *(const float4*)(gW + (size_t)b * DD + d0);
    float4 vv = *(const float4*)(vp + d0);
    for (int s = wave; s < SS; s += 4) {
        float4 r = *(const float4*)(refp + ((size_t)b * SS + s) * DD + d0);
        float sum = vv.x * tanhf(r.x + gw.x) + vv.y * tanhf(r.y + gw.y) +
                    vv.z * tanhf(r.z + gw.z) + vv.w * tanhf(r.w + gw.w);
#pragma unroll
        for (int off = 32; off; off >>= 1) sum += __shfl_xor(sum, off);
        if (lane == 0) ash[s] = sum;
    }
    __syncthreads();
    if (t < 64) {
        float logit = (t < SS && mask[b * SS + t] == 0.0f) ? ash[t]
                                                           : -__builtin_inff();
        float m = logit;
#pragma unroll
        for (int off = 32; off; off >>= 1) m = fmaxf(m, __shfl_xor(m, off));
        int cand = (logit == m) ? t : (1 << 30);
#pragma unroll
        for (int off = 32; off; off >>= 1) cand = min(cand, __shfl_xor(cand, off));
        float e = expf(logit - m);
        float se = e;
#pragma unroll
        for (int off = 32; off; off >>= 1) se += __shfl_xor(se, off);
        if (t == 0) {
            float lpn = lp[b] - logf(se);
            lp[b] = lpn;
            outp[(size_t)b * STEPS + step] = (float)cand;
            mask[b * SS + cand] = 1.0f;
            if (step == STEPS - 1) outp[(size_t)BB * STEPS + b] = lpn;
            ssel = cand;
        }
    }
    __syncthreads();
    x[(size_t)b * DD + t] = enc[((size_t)ssel * BB + b) * DD + t];
}

// ---------------------------------------------------------------------------
extern "C" void kernel_launch(void* const* d_in, const int* in_sizes, int n_in,
                              void* d_out, int out_size, void* d_ws, size_t ws_size,
                              hipStream_t stream) {
    const float* enc    = (const float*)d_in[0];
    const float* h0     = (const float*)d_in[1];
    const float* c0     = (const float*)d_in[2];
    const float* rk     = (const float*)d_in[3];
    const float* Wfirst = (const float*)d_in[4];
    const float* bfirst = (const float*)d_in[5];
    const float* Wih_f  = (const float*)d_in[6];
    const float* Whh_f  = (const float*)d_in[7];
    const float* bih_f  = (const float*)d_in[8];
    const float* bhh_f  = (const float*)d_in[9];
    const float* Wih_b  = (const float*)d_in[10];
    const float* Whh_b  = (const float*)d_in[11];
    const float* bih_b  = (const float*)d_in[12];
    const float* bhh_b  = (const float*)d_in[13];
    const float* Wref_g = (const float*)d_in[14];
    const float* Wq_g   = (const float*)d_in[15];
    const float* vg     = (const float*)d_in[16];
    const float* Wref   = (const float*)d_in[17];
    const float* Wq     = (const float*)d_in[18];
    const float* v      = (const float*)d_in[19];
    float* out = (float*)d_out;

    float* ws    = (float*)d_ws;
    float* refg  = ws;
    float* refp  = refg + (size_t)BB * SS * DD;
    float* x     = refp + (size_t)BB * SS * DD;
    float* q     = x + (size_t)BB * DD;
    float* c     = q + (size_t)BB * DD;
    float* gates = c + (size_t)2 * BB * HH;
    float* qW    = gates + (size_t)BB * 1024;
    float* gl    = qW + (size_t)BB * DD;
    float* gWb   = gl + (size_t)BB * DD;
    float* maskb = gWb + (size_t)BB * DD;
    float* lp    = maskb + (size_t)BB * SS;

    k_init<<<dim3(BB * DD / 256), dim3(256), 0, stream>>>(h0, c0, rk, Wfirst,
                                                          bfirst, x, q, c, maskb, lp);
    k_refdot<<<dim3(BB * SS / 64, 1, 2), dim3(256), 0, stream>>>(enc, Wref_g, Wref,
                                                                 refg, refp);
    for (int step = 0; step < STEPS; ++step) {
        k_gates<<<dim3(32, 8, 2), dim3(256), 0, stream>>>(
            x, q, Wih_f, Whh_f, bih_f, bhh_f, Wih_b, Whh_b, bih_b, bhh_b, gates);
        k_lstm_pw<<<dim3(2 * BB * HH / 256), dim3(256), 0, stream>>>(gates, q, c);
        k_proj<<<dim3(32, 4), dim3(256), 0, stream>>>(q, Wq_g, qW);
        k_glimpse<<<dim3(BB), dim3(256), 0, stream>>>(refg, qW, vg, enc, maskb, gl);
        k_proj<<<dim3(32, 4), dim3(256), 0, stream>>>(gl, Wq, gWb);
        k_pointer<<<dim3(BB), dim3(256), 0, stream>>>(refp, gWb, v, enc, maskb, x,
                                                      lp, out, step);
    }
}

// Round 4
// 4834.102 us; speedup vs baseline: 1.5303x; 1.5303x over previous
//
#include <hip/hip_runtime.h>
#include <math.h>

#define SS 50
#define BB 2048
#define HH 128
#define DD 256
#define STEPS 49
#define NREF ((size_t)BB * SS * DD)   // 26,214,400 floats per ref tensor

__device__ __forceinline__ float sigmoidf_(float x) { return 1.0f / (1.0f + expf(-x)); }

// ---------------------------------------------------------------------------
// K0: init — x0 = tanh(fe @ W_first^T + b_first), q <- [h0_f | h0_b], c <- c0,
// unmasked-list = identity, lp = 0.   grid = B*D/256
// ---------------------------------------------------------------------------
__global__ __launch_bounds__(256) void k_init(
    const float* __restrict__ h0, const float* __restrict__ c0,
    const float* __restrict__ rk, const float* __restrict__ Wf,
    const float* __restrict__ bf,
    float* __restrict__ x, float* __restrict__ q, float* __restrict__ c,
    int* __restrict__ unm, float* __restrict__ lp)
{
    int idx = blockIdx.x * 256 + threadIdx.x;      // 0 .. B*D-1 == 0 .. 2*B*H-1
    int b = idx >> 8, d = idx & 255;
    float inv = 1.0f / rk[b];
    float t0 = 1.1f * Wf[2 * d] + inv * Wf[2 * d + 1];
    x[idx] = tanhf(t0 + bf[d]);
    q[idx] = (d < HH) ? h0[b * HH + d] : h0[BB * HH + b * HH + (d - HH)];
    c[idx] = c0[idx];
    if (idx < BB * 64) unm[idx] = idx & 63;        // list entries >=50 never read
    if (idx < BB) lp[idx] = 0.0f;
}

// ---------------------------------------------------------------------------
// P1: refX[b][s][d] = sum_e WX[d][e] * enc[s][b][e]  for X in {g, p, q}
// M = B*S rows, N = D = 256 (full width per block), K = 256.
// tile 64(M) x 256(N), 256 threads, acc 4x16.  grid (1600, 1, 2 or 3)
// ---------------------------------------------------------------------------
__global__ __launch_bounds__(256) void k_refdot(
    const float* __restrict__ enc, const float* __restrict__ Wg,
    const float* __restrict__ Wp, const float* __restrict__ Wqq,
    float* __restrict__ refg, float* __restrict__ refp, float* __restrict__ refq)
{
    const float* W = (blockIdx.z == 0) ? Wg : (blockIdx.z == 1) ? Wp : Wqq;
    float* out = (blockIdx.z == 0) ? refg : (blockIdx.z == 1) ? refp : refq;
    __shared__ float As[16][68];
    __shared__ float Ws[16][264];
    int t = threadIdx.x;
    int m0 = blockIdx.x * 64;
    int rr = t >> 2, kk = (t & 3) << 2;
    int n = m0 + rr;
    int ab = n / SS, as = n - ab * SS;
    const float* arow = enc + ((size_t)as * BB + ab) * DD + kk;
    const float* wrow = W + (size_t)t * DD;
    int tm = (t & 15) << 2;
    int tn = (t >> 4) << 4;
    float acc[4][16];
#pragma unroll
    for (int i = 0; i < 4; i++)
#pragma unroll
        for (int j = 0; j < 16; j++) acc[i][j] = 0.0f;

    for (int k0 = 0; k0 < DD; k0 += 16) {
        float4 av = *(const float4*)(arow + k0);
        float4 w0 = *(const float4*)(wrow + k0);
        float4 w1 = *(const float4*)(wrow + k0 + 4);
        float4 w2 = *(const float4*)(wrow + k0 + 8);
        float4 w3 = *(const float4*)(wrow + k0 + 12);
        __syncthreads();
        As[kk + 0][rr] = av.x; As[kk + 1][rr] = av.y;
        As[kk + 2][rr] = av.z; As[kk + 3][rr] = av.w;
        Ws[0][t] = w0.x;  Ws[1][t] = w0.y;  Ws[2][t] = w0.z;  Ws[3][t] = w0.w;
        Ws[4][t] = w1.x;  Ws[5][t] = w1.y;  Ws[6][t] = w1.z;  Ws[7][t] = w1.w;
        Ws[8][t] = w2.x;  Ws[9][t] = w2.y;  Ws[10][t] = w2.z; Ws[11][t] = w2.w;
        Ws[12][t] = w3.x; Ws[13][t] = w3.y; Ws[14][t] = w3.z; Ws[15][t] = w3.w;
        __syncthreads();
#pragma unroll
        for (int k = 0; k < 16; k++) {
            float4 a = *(const float4*)&As[k][tm];
            float aa[4] = {a.x, a.y, a.z, a.w};
#pragma unroll
            for (int jj = 0; jj < 4; jj++) {
                float4 w = *(const float4*)&Ws[k][tn + (jj << 2)];
                float ww[4] = {w.x, w.y, w.z, w.w};
#pragma unroll
                for (int i = 0; i < 4; i++)
#pragma unroll
                    for (int cj = 0; cj < 4; cj++)
                        acc[i][jj * 4 + cj] = fmaf(aa[i], ww[cj], acc[i][jj * 4 + cj]);
            }
        }
    }
#pragma unroll
    for (int i = 0; i < 4; i++) {
        float* orow = out + (size_t)(m0 + tm + i) * DD + tn;
#pragma unroll
        for (int jj = 0; jj < 4; jj++) {
            float4 o = make_float4(acc[i][jj * 4], acc[i][jj * 4 + 1],
                                   acc[i][jj * 4 + 2], acc[i][jj * 4 + 3]);
            *(float4*)(orow + (jj << 2)) = o;
        }
    }
}

// ---------------------------------------------------------------------------
// K1: gates GEMM.  M=2048, N=512 (per dir), K=384. tile 64x64. grid (32,8,2)
// ---------------------------------------------------------------------------
__global__ __launch_bounds__(256) void k_gates(
    const float* __restrict__ x, const float* __restrict__ q,
    const float* __restrict__ Wih_f, const float* __restrict__ Whh_f,
    const float* __restrict__ bih_f, const float* __restrict__ bhh_f,
    const float* __restrict__ Wih_b, const float* __restrict__ Whh_b,
    const float* __restrict__ bih_b, const float* __restrict__ bhh_b,
    float* __restrict__ gates)
{
    int z = blockIdx.z;
    const float* Wih = z ? Wih_b : Wih_f;
    const float* Whh = z ? Whh_b : Whh_f;
    const float* bih = z ? bih_b : bih_f;
    const float* bhh = z ? bhh_b : bhh_f;
    __shared__ float As[16][68];
    __shared__ float Ws[16][68];
    int t = threadIdx.x;
    int m0 = blockIdx.x * 64, n0 = blockIdx.y * 64;
    int rr = t >> 2, kk = (t & 3) << 2;
    int tm = (t & 15) << 2, tn = (t >> 4) << 2;
    float acc[4][4] = {};
    for (int k0 = 0; k0 < 384; k0 += 16) {
        float4 av, wv;
        if (k0 < 256) {
            av = *(const float4*)(x + (size_t)(m0 + rr) * DD + k0 + kk);
            wv = *(const float4*)(Wih + (size_t)(n0 + rr) * DD + k0 + kk);
        } else {
            av = *(const float4*)(q + (size_t)(m0 + rr) * DD + (z << 7) + (k0 - 256) + kk);
            wv = *(const float4*)(Whh + (size_t)(n0 + rr) * HH + (k0 - 256) + kk);
        }
        __syncthreads();
        As[kk + 0][rr] = av.x; As[kk + 1][rr] = av.y;
        As[kk + 2][rr] = av.z; As[kk + 3][rr] = av.w;
        Ws[kk + 0][rr] = wv.x; Ws[kk + 1][rr] = wv.y;
        Ws[kk + 2][rr] = wv.z; Ws[kk + 3][rr] = wv.w;
        __syncthreads();
#pragma unroll
        for (int k = 0; k < 16; k++) {
            float4 a = *(const float4*)&As[k][tm];
            float4 w = *(const float4*)&Ws[k][tn];
            float aa[4] = {a.x, a.y, a.z, a.w};
            float ww[4] = {w.x, w.y, w.z, w.w};
#pragma unroll
            for (int i = 0; i < 4; i++)
#pragma unroll
                for (int j = 0; j < 4; j++)
                    acc[i][j] = fmaf(aa[i], ww[j], acc[i][j]);
        }
    }
#pragma unroll
    for (int i = 0; i < 4; i++) {
        int col = n0 + tn;
        float4 o;
        o.x = acc[i][0] + bih[col + 0] + bhh[col + 0];
        o.y = acc[i][1] + bih[col + 1] + bhh[col + 1];
        o.z = acc[i][2] + bih[col + 2] + bhh[col + 2];
        o.w = acc[i][3] + bih[col + 3] + bhh[col + 3];
        *(float4*)(gates + (size_t)(m0 + tm + i) * 1024 + (z << 9) + col) = o;
    }
}

// ---------------------------------------------------------------------------
// K2: LSTM pointwise.  idx over 2*B*H.  grid 2048
// ---------------------------------------------------------------------------
__global__ __launch_bounds__(256) void k_lstm_pw(
    const float* __restrict__ gates, float* __restrict__ q, float* __restrict__ c)
{
    int idx = blockIdx.x * 256 + threadIdx.x;   // 0 .. 2*B*H-1
    int z = idx >> 18;                          // B*H = 2^18
    int r = idx & (BB * HH - 1);
    int b = r >> 7, hh = r & 127;
    const float* gb = gates + (size_t)b * 1024 + (z << 9);
    float ig = sigmoidf_(gb[hh]);
    float fg = sigmoidf_(gb[128 + hh]);
    float gg = tanhf(gb[256 + hh]);
    float og = sigmoidf_(gb[384 + hh]);
    float c2 = fg * c[idx] + ig * gg;
    c[idx] = c2;
    q[(size_t)b * DD + (z << 7) + hh] = og * tanhf(c2);
}

// ---------------------------------------------------------------------------
// K3: out[b][d] = sum_e A[b][e] * W[d][e]   (M=2048,N=256,K=256). grid (32,4)
// ---------------------------------------------------------------------------
__global__ __launch_bounds__(256) void k_proj(
    const float* __restrict__ A, const float* __restrict__ W, float* __restrict__ out)
{
    __shared__ float As[16][68];
    __shared__ float Ws[16][68];
    int t = threadIdx.x;
    int m0 = blockIdx.x * 64, n0 = blockIdx.y * 64;
    int rr = t >> 2, kk = (t & 3) << 2;
    int tm = (t & 15) << 2, tn = (t >> 4) << 2;
    const float* arow = A + (size_t)(m0 + rr) * DD + kk;
    const float* wrow = W + (size_t)(n0 + rr) * DD + kk;
    float acc[4][4] = {};
    for (int k0 = 0; k0 < DD; k0 += 16) {
        float4 av = *(const float4*)(arow + k0);
        float4 wv = *(const float4*)(wrow + k0);
        __syncthreads();
        As[kk + 0][rr] = av.x; As[kk + 1][rr] = av.y;
        As[kk + 2][rr] = av.z; As[kk + 3][rr] = av.w;
        Ws[kk + 0][rr] = wv.x; Ws[kk + 1][rr] = wv.y;
        Ws[kk + 2][rr] = wv.z; Ws[kk + 3][rr] = wv.w;
        __syncthreads();
#pragma unroll
        for (int k = 0; k < 16; k++) {
            float4 a = *(const float4*)&As[k][tm];
            float4 w = *(const float4*)&Ws[k][tn];
            float aa[4] = {a.x, a.y, a.z, a.w};
            float ww[4] = {w.x, w.y, w.z, w.w};
#pragma unroll
            for (int i = 0; i < 4; i++)
#pragma unroll
                for (int j = 0; j < 4; j++)
                    acc[i][j] = fmaf(aa[i], ww[j], acc[i][j]);
        }
    }
#pragma unroll
    for (int i = 0; i < 4; i++) {
        float4 o = make_float4(acc[i][0], acc[i][1], acc[i][2], acc[i][3]);
        *(float4*)(out + (size_t)(m0 + tm + i) * DD + n0 + tn) = o;
    }
}

// ---------------------------------------------------------------------------
// KG: glimpse. one block per b; u_g over UNMASKED rows only -> softmax -> a.
// In fallback mode (gl != nullptr) also computes g_l from enc.  grid (B), 256
// ---------------------------------------------------------------------------
__global__ __launch_bounds__(256) void k_glimpse(
    const float* __restrict__ refg, const float* __restrict__ qW,
    const float* __restrict__ vg, const float* __restrict__ enc,
    const int* __restrict__ unm, float* __restrict__ a,
    float* __restrict__ gl, int cnt)
{
    int b = blockIdx.x;
    int t = threadIdx.x, wave = t >> 6, lane = t & 63;
    __shared__ float ash[SS];
    __shared__ int sl[SS];
    if (t < cnt) sl[t] = unm[b * 64 + t];
    __syncthreads();
    int d0 = lane << 2;
    float4 qw = *(const float4*)(qW + (size_t)b * DD + d0);
    float4 vv = *(const float4*)(vg + d0);
    for (int li = wave; li < cnt; li += 4) {
        int s = sl[li];
        float4 r = *(const float4*)(refg + ((size_t)b * SS + s) * DD + d0);
        float sum = vv.x * tanhf(r.x + qw.x) + vv.y * tanhf(r.y + qw.y) +
                    vv.z * tanhf(r.z + qw.z) + vv.w * tanhf(r.w + qw.w);
#pragma unroll
        for (int off = 32; off; off >>= 1) sum += __shfl_xor(sum, off);
        if (lane == 0) ash[li] = sum;
    }
    __syncthreads();
    if (t < 64) {
        float logit = (t < cnt) ? ash[t] : -__builtin_inff();
        float m = logit;
#pragma unroll
        for (int off = 32; off; off >>= 1) m = fmaxf(m, __shfl_xor(m, off));
        float e = expf(logit - m);
        float ssum = e;
#pragma unroll
        for (int off = 32; off; off >>= 1) ssum += __shfl_xor(ssum, off);
        if (t < cnt) {
            float av = e / ssum;
            ash[t] = av;
            a[b * 64 + t] = av;
        }
    }
    __syncthreads();
    if (gl) {
        float accv = 0.0f;
        for (int li = 0; li < cnt; ++li)
            accv = fmaf(ash[li], enc[((size_t)sl[li] * BB + b) * DD + t], accv);
        gl[(size_t)b * DD + t] = accv;
    }
}

// ---------------------------------------------------------------------------
// KP: pointer. gW from refq (or gWin in fallback); u_p over UNMASKED rows;
// argmax (min-s tie-break) -> lp, list swap-remove, sel, gather next input.
// grid (B), 256 thr
// ---------------------------------------------------------------------------
__global__ __launch_bounds__(256) void k_pointer(
    const float* __restrict__ refp, const float* __restrict__ refq,
    const float* __restrict__ gWin, const float* __restrict__ vp,
    const float* __restrict__ enc, int* __restrict__ unm,
    const float* __restrict__ a, float* __restrict__ lp,
    float* __restrict__ x, float* __restrict__ outp, int step, int cnt)
{
    int b = blockIdx.x;
    int t = threadIdx.x, wave = t >> 6, lane = t & 63;
    __shared__ float ash[SS];
    __shared__ int sl[SS];
    __shared__ float gw[DD];
    __shared__ int ssel;
    if (t < cnt) { sl[t] = unm[b * 64 + t]; ash[t] = a[b * 64 + t]; }
    __syncthreads();
    if (refq) {
        float accg = 0.0f;
        for (int li = 0; li < cnt; ++li)
            accg = fmaf(ash[li], refq[((size_t)b * SS + sl[li]) * DD + t], accg);
        gw[t] = accg;
    } else {
        gw[t] = gWin[(size_t)b * DD + t];
    }
    __syncthreads();
    int d0 = lane << 2;
    float4 g4 = *(const float4*)(gw + d0);
    float4 vv = *(const float4*)(vp + d0);
    // ash reused for u_p values (a no longer needed)
    for (int li = wave; li < cnt; li += 4) {
        int s = sl[li];
        float4 r = *(const float4*)(refp + ((size_t)b * SS + s) * DD + d0);
        float sum = vv.x * tanhf(r.x + g4.x) + vv.y * tanhf(r.y + g4.y) +
                    vv.z * tanhf(r.z + g4.z) + vv.w * tanhf(r.w + g4.w);
#pragma unroll
        for (int off = 32; off; off >>= 1) sum += __shfl_xor(sum, off);
        if (lane == 0) ash[li] = sum;
    }
    __syncthreads();
    if (t < 64) {
        float logit = (t < cnt) ? ash[t] : -__builtin_inff();
        int skey = (t < cnt) ? (sl[t] * 64 + t) : (1 << 30);
        float m = logit;
#pragma unroll
        for (int off = 32; off; off >>= 1) m = fmaxf(m, __shfl_xor(m, off));
        int cand = (logit == m) ? skey : (1 << 30);
#pragma unroll
        for (int off = 32; off; off >>= 1) cand = min(cand, __shfl_xor(cand, off));
        float e = expf(logit - m);
        float se = e;
#pragma unroll
        for (int off = 32; off; off >>= 1) se += __shfl_xor(se, off);
        if (t == 0) {
            int s_sel = cand >> 6, posl = cand & 63;
            float lpn = lp[b] - logf(se);
            lp[b] = lpn;
            outp[(size_t)b * STEPS + step] = (float)s_sel;
            if (step == STEPS - 1) outp[(size_t)BB * STEPS + b] = lpn;
            unm[b * 64 + posl] = sl[cnt - 1];   // swap-remove
            ssel = s_sel;
        }
    }
    __syncthreads();
    x[(size_t)b * DD + t] = enc[((size_t)ssel * BB + b) * DD + t];
}

// ---------------------------------------------------------------------------
extern "C" void kernel_launch(void* const* d_in, const int* in_sizes, int n_in,
                              void* d_out, int out_size, void* d_ws, size_t ws_size,
                              hipStream_t stream) {
    const float* enc    = (const float*)d_in[0];
    const float* h0     = (const float*)d_in[1];
    const float* c0     = (const float*)d_in[2];
    const float* rk     = (const float*)d_in[3];
    const float* Wfirst = (const float*)d_in[4];
    const float* bfirst = (const float*)d_in[5];
    const float* Wih_f  = (const float*)d_in[6];
    const float* Whh_f  = (const float*)d_in[7];
    const float* bih_f  = (const float*)d_in[8];
    const float* bhh_f  = (const float*)d_in[9];
    const float* Wih_b  = (const float*)d_in[10];
    const float* Whh_b  = (const float*)d_in[11];
    const float* bih_b  = (const float*)d_in[12];
    const float* bhh_b  = (const float*)d_in[13];
    const float* Wref_g = (const float*)d_in[14];
    const float* Wq_g   = (const float*)d_in[15];
    const float* vg     = (const float*)d_in[16];
    const float* Wref   = (const float*)d_in[17];
    const float* Wq     = (const float*)d_in[18];
    const float* v      = (const float*)d_in[19];
    float* out = (float*)d_out;

    float* ws    = (float*)d_ws;
    float* refg  = ws;
    float* refp  = refg + NREF;
    float* x     = refp + NREF;
    float* q     = x + (size_t)BB * DD;
    float* c     = q + (size_t)BB * DD;
    float* gates = c + (size_t)BB * DD;
    float* qWb   = gates + (size_t)BB * 1024;
    float* gl    = qWb + (size_t)BB * DD;
    float* gWb   = gl + (size_t)BB * DD;
    float* a     = gWb + (size_t)BB * DD;
    float* lp    = a + (size_t)BB * 64;
    int*   unm   = (int*)(lp + BB);
    float* refq  = (float*)(unm + (size_t)BB * 64);   // optional tail

    size_t need_refq = ((size_t)(refq - ws) + NREF) * sizeof(float);
    bool useRefq = ws_size >= need_refq;

    k_init<<<dim3(BB * DD / 256), dim3(256), 0, stream>>>(h0, c0, rk, Wfirst,
                                                          bfirst, x, q, c, unm, lp);
    k_refdot<<<dim3(BB * SS / 64, 1, useRefq ? 3 : 2), dim3(256), 0, stream>>>(
        enc, Wref_g, Wref, Wq, refg, refp, refq);
    for (int step = 0; step < STEPS; ++step) {
        int cnt = SS - step;
        k_gates<<<dim3(32, 8, 2), dim3(256), 0, stream>>>(
            x, q, Wih_f, Whh_f, bih_f, bhh_f, Wih_b, Whh_b, bih_b, bhh_b, gates);
        k_lstm_pw<<<dim3(2 * BB * HH / 256), dim3(256), 0, stream>>>(gates, q, c);
        k_proj<<<dim3(32, 4), dim3(256), 0, stream>>>(q, Wq_g, qWb);
        k_glimpse<<<dim3(BB), dim3(256), 0, stream>>>(refg, qWb, vg, enc, unm, a,
                                                      useRefq ? nullptr : gl, cnt);
        if (!useRefq)
            k_proj<<<dim3(32, 4), dim3(256), 0, stream>>>(gl, Wq, gWb);
        k_pointer<<<dim3(BB), dim3(256), 0, stream>>>(refp, useRefq ? refq : nullptr,
                                                      gWb, v, enc, unm, a, lp, x, out,
                                                      step, cnt);
    }
}